// Round 4
// baseline (758.330 us; speedup 1.0000x reference)
//
#include <hip/hip_runtime.h>

#define NE 8
#define DD 1024
#define HH 2816
#define TT 16384
#define MT (TT / 128 + NE)  // 136 static M-tiles (128-row)

constexpr int NJA = MT * (HH / 128);  // 2992, %8==0 -> bijective XCD swizzle
constexpr int NJB = MT * (DD / 256);  // 544, %8==0
constexpr int ZBLK = 64;              // tail-zero blocks appended to down_gemm grid

typedef __bf16 bf16;
typedef __bf16 bf16x4 __attribute__((ext_vector_type(4)));
typedef __bf16 bf16x8 __attribute__((ext_vector_type(8)));
typedef float f32x4 __attribute__((ext_vector_type(4)));

// ---- workspace layout (bytes), unchanged ----
constexpr size_t HBUF_E = (size_t)TT * HH;
constexpr size_t XN = (size_t)TT * DD;
constexpr size_t WN = (size_t)NE * HH * DD;
constexpr size_t XB_OFF = HBUF_E * 2;
constexpr size_t W1B_OFF = XB_OFF + XN * 2;
constexpr size_t W3B_OFF = W1B_OFF + WN * 2;

__device__ __forceinline__ void gld16(const void* g, void* l) {
  __builtin_amdgcn_global_load_lds(
      (const __attribute__((address_space(1))) void*)g,
      (__attribute__((address_space(3))) void*)l, 16, 0, 0);
}

__device__ __forceinline__ f32x4 mfma16(bf16x8 a, bf16x8 b, f32x4 c) {
  return __builtin_amdgcn_mfma_f32_16x16x32_bf16(a, b, c, 0, 0, 0);
}

#define BARRIER()                      \
  do {                                 \
    __builtin_amdgcn_s_barrier();      \
    asm volatile("" ::: "memory");     \
  } while (0)

// fused fp32->bf16 convert for x, w1, w3 in one dispatch
__global__ __launch_bounds__(256) void cvt3_k(
    const float4* __restrict__ x, const float4* __restrict__ w1,
    const float4* __restrict__ w3, bf16x4* __restrict__ xb,
    bf16x4* __restrict__ w1b, bf16x4* __restrict__ w3b) {
  constexpr int NBX = (int)(XN / 4 / 256);  // 16384
  constexpr int NBW = (int)(WN / 4 / 256);  // 22528
  int b = blockIdx.x;
  const float4* src;
  bf16x4* dst;
  int i;
  if (b < NBX) {
    src = x; dst = xb; i = b * 256 + threadIdx.x;
  } else if (b < NBX + NBW) {
    src = w1; dst = w1b; i = (b - NBX) * 256 + threadIdx.x;
  } else {
    src = w3; dst = w3b; i = (b - NBX - NBW) * 256 + threadIdx.x;
  }
  float4 v = src[i];
  bf16x4 o;
  o[0] = (bf16)v.x; o[1] = (bf16)v.y; o[2] = (bf16)v.z; o[3] = (bf16)v.w;
  dst[i] = o;
}

// single-matrix convert (w2, after GEMM A frees its alias)
__global__ __launch_bounds__(256) void cvt_bf16_k(const float4* __restrict__ in,
                                                  bf16x4* __restrict__ out, int n4) {
  int i = blockIdx.x * 256 + threadIdx.x;
  if (i < n4) {
    float4 v = in[i];
    bf16x4 o;
    o[0] = (bf16)v.x; o[1] = (bf16)v.y; o[2] = (bf16)v.z; o[3] = (bf16)v.w;
    out[i] = o;
  }
}

struct TileInfo { int e, row0, rv; };
__device__ __forceinline__ TileInfo find_tile(const int* __restrict__ cnts, int t) {
  TileInfo ti; ti.e = -1; ti.row0 = 0; ti.rv = 0;
  int off = 0;
#pragma unroll
  for (int i = 0; i < NE; ++i) {
    int c = cnts[i];
    int tl = (c + 127) >> 7;
    if (ti.e < 0) {
      if (t < tl) {
        ti.e = i;
        ti.row0 = off + (t << 7);
        int rv = c - (t << 7);
        ti.rv = rv > 128 ? 128 : rv;
      } else {
        t -= tl;
      }
    }
    off += c;
  }
  return ti;
}

// ============================================================================
// Kernel A: h = silu(x@w1[e]^T) * (x@w3[e]^T)
// m201-style fine-phase schedule: BM=128, BN=128 per matrix, BK=64.
// 512 thr = 8 waves (2M x 4N); per wave 64x32 of each matrix.
// Triple-buffered LDS (144 KB, 1 blk/CU); K-tile = 2 phases x 16 MFMA, each
// phase: {frag ds_reads; stage slice of tile kt+2; BARRIER; setprio+MFMA;
// BARRIER}; vmcnt(6) once per K-tile (never 0 in steady state).
// Full 3-bit involution swizzle (chunk ^= row&7) for BK=64 rows (128 B).
// ============================================================================
__global__ __launch_bounds__(512, 2) void swiglu_gemm_k(
    const bf16* __restrict__ x, const bf16* __restrict__ w1,
    const bf16* __restrict__ w3, const int* __restrict__ cnts,
    bf16* __restrict__ hbuf) {
  constexpr int NKT = DD / 64;  // 16 K-tiles

  int lin = blockIdx.x;
  lin = (lin & 7) * (NJA / 8) + (lin >> 3);  // bijective XCD swizzle
  const int tile = lin % MT;                 // tile-minor: weight slab L2-hot
  const int n0 = (lin / MT) * 128;
  TileInfo ti = find_tile(cnts, tile);
  if (ti.e < 0) return;

  const bf16* w1e = w1 + (size_t)ti.e * HH * DD;
  const bf16* w3e = w3 + (size_t)ti.e * HH * DD;
  const bf16* xb = x + (size_t)ti.row0 * DD;

  __shared__ bf16 sA[3][128 * 64];   // 16 KB / buf
  __shared__ bf16 sB1[3][128 * 64];  // 16 KB / buf
  __shared__ bf16 sB3[3][128 * 64];  // 16 KB / buf -> 144 KB total

  const int tid = threadIdx.x;
  const int lane = tid & 63, wave = tid >> 6;
  const int wm = wave >> 2, wn = wave & 3;
  const int lr = lane & 15, lkg = (lane >> 4) & 3;

  // ---- staging: linear LDS dest (gld16 req), inverse-swizzled global src ----
  const int r8 = tid >> 3;                             // LDS row 0..63
  const int csw = ((tid & 7) ^ (r8 & 7)) << 3;         // swizzled col (elems)
  const int rvm1 = ti.rv - 1;
  const int ra0 = r8 > rvm1 ? rvm1 : r8;
  const int ra1 = (64 + r8) > rvm1 ? rvm1 : 64 + r8;
  const bf16* gA0 = xb + (size_t)ra0 * DD + csw;
  const bf16* gA1 = xb + (size_t)ra1 * DD + csw;
  const bf16* gB1a = w1e + (size_t)(n0 + r8) * DD + csw;
  const bf16* gB1b = w1e + (size_t)(n0 + 64 + r8) * DD + csw;
  const bf16* gB3a = w3e + (size_t)(n0 + r8) * DD + csw;
  const bf16* gB3b = w3e + (size_t)(n0 + 64 + r8) * DD + csw;
  const int d0 = tid * 8, d1 = 4096 + tid * 8;

// per K-tile per wave: P0 issues 4 loads, P1 issues 2 -> 6 (matches vmcnt ring)
#define STAGE_A_P0(kt, bb)               \
  do {                                   \
    int kk = (kt) * 64;                  \
    gld16(gA0 + kk, &sA[bb][d0]);        \
    gld16(gA1 + kk, &sA[bb][d1]);        \
    gld16(gB1a + kk, &sB1[bb][d0]);      \
    gld16(gB1b + kk, &sB1[bb][d1]);      \
  } while (0)
#define STAGE_A_P1(kt, bb)               \
  do {                                   \
    int kk = (kt) * 64;                  \
    gld16(gB3a + kk, &sB3[bb][d0]);      \
    gld16(gB3b + kk, &sB3[bb][d1]);      \
  } while (0)

  // ---- frag read offsets (bytes): row*128 + ((chunk ^ (row&7))<<4) ----
  // row&7 == lr&7 (row bases are multiples of 16); ks=1 toggles chunk bit2 (^64)
  const int s7 = lr & 7;
  const int abase = (wm * 64 + lr) * 128 + ((lkg ^ s7) << 4);  // + mt*2048
  const int bbase = (wn * 32 + lr) * 128 + ((lkg ^ s7) << 4);  // + nt*2048

  f32x4 acc1[4][2], acc3[4][2];
#pragma unroll
  for (int i = 0; i < 4; ++i)
#pragma unroll
    for (int j = 0; j < 2; ++j) {
      acc1[i][j] = f32x4{0.f, 0.f, 0.f, 0.f};
      acc3[i][j] = f32x4{0.f, 0.f, 0.f, 0.f};
    }

  STAGE_A_P0(0, 0); STAGE_A_P1(0, 0);
  STAGE_A_P0(1, 1); STAGE_A_P1(1, 1);
  asm volatile("s_waitcnt vmcnt(6)" ::: "memory");  // tile0 landed (per wave)
  BARRIER();                                        // aggregate across waves

  int cur = 0;
  for (int kt = 0; kt < NKT; ++kt) {
    const bool pf = (kt + 2) < NKT;
    int nxt = cur + 2; if (nxt >= 3) nxt -= 3;  // == buf of kt-1, reads done
    const char* pA = (const char*)sA[cur];
    const char* pB1 = (const char*)sB1[cur];
    const char* pB3 = (const char*)sB3[cur];

    bf16x8 af[4], f1[2], f3[2];
    // ---- phase 0 (ks=0) ----
#pragma unroll
    for (int mt = 0; mt < 4; ++mt)
      af[mt] = *(const bf16x8*)(pA + abase + mt * 2048);
#pragma unroll
    for (int nt = 0; nt < 2; ++nt) {
      f1[nt] = *(const bf16x8*)(pB1 + bbase + nt * 2048);
      f3[nt] = *(const bf16x8*)(pB3 + bbase + nt * 2048);
    }
    if (pf) STAGE_A_P0(kt + 2, nxt);
    BARRIER();
    __builtin_amdgcn_s_setprio(1);
#pragma unroll
    for (int mt = 0; mt < 4; ++mt)
#pragma unroll
      for (int nt = 0; nt < 2; ++nt) {
        acc1[mt][nt] = mfma16(f1[nt], af[mt], acc1[mt][nt]);  // swapped operands
        acc3[mt][nt] = mfma16(f3[nt], af[mt], acc3[mt][nt]);
      }
    __builtin_amdgcn_s_setprio(0);
    BARRIER();

    // ---- phase 1 (ks=1): chunk ^64 ----
#pragma unroll
    for (int mt = 0; mt < 4; ++mt)
      af[mt] = *(const bf16x8*)(pA + ((abase + mt * 2048) ^ 64));
#pragma unroll
    for (int nt = 0; nt < 2; ++nt) {
      f1[nt] = *(const bf16x8*)(pB1 + ((bbase + nt * 2048) ^ 64));
      f3[nt] = *(const bf16x8*)(pB3 + ((bbase + nt * 2048) ^ 64));
    }
    if (pf) STAGE_A_P1(kt + 2, nxt);
    // boundary wait: per-wave, own tile-(kt+1) slice landed; barrier aggregates
    if (pf) asm volatile("s_waitcnt vmcnt(6)" ::: "memory");
    else    asm volatile("s_waitcnt vmcnt(0)" ::: "memory");
    BARRIER();
    __builtin_amdgcn_s_setprio(1);
#pragma unroll
    for (int mt = 0; mt < 4; ++mt)
#pragma unroll
      for (int nt = 0; nt < 2; ++nt) {
        acc1[mt][nt] = mfma16(f1[nt], af[mt], acc1[mt][nt]);
        acc3[mt][nt] = mfma16(f3[nt], af[mt], acc3[mt][nt]);
      }
    __builtin_amdgcn_s_setprio(0);
    BARRIER();
    cur = (cur + 1 == 3) ? 0 : cur + 1;
  }
#undef STAGE_A_P0
#undef STAGE_A_P1

  // epilogue: swapped layout -> m = lr, n = lkg*4 + reg (4 consecutive cols)
#pragma unroll
  for (int mt = 0; mt < 4; ++mt) {
    int row = wm * 64 + mt * 16 + lr;
    if (row < ti.rv) {
      size_t base = (size_t)(ti.row0 + row) * HH + n0 + wn * 32 + (lkg << 2);
#pragma unroll
      for (int nt = 0; nt < 2; ++nt) {
        bf16x4 o;
#pragma unroll
        for (int r = 0; r < 4; ++r) {
          float a = acc1[mt][nt][r], b = acc3[mt][nt][r];
          o[r] = (bf16)(a / (1.f + __expf(-a)) * b);
        }
        *(bf16x4*)&hbuf[base + nt * 16] = o;
      }
    }
  }
}

// ============================================================================
// Kernel B: out = h @ w2[e]^T. Same phase template. BM=128, BN=256, BK=64,
// 512 thr (2M x 4N waves, 64x64 out/wave), 144 KB triple-buffer, vmcnt(6).
// Tail blocks (>= NJB) zero the padding rows.
// ============================================================================
__global__ __launch_bounds__(512, 2) void down_gemm_k(
    const bf16* __restrict__ hbuf, const bf16* __restrict__ w2,
    const int* __restrict__ cnts, float* __restrict__ out) {
  constexpr int NKT = HH / 64;  // 44 K-tiles

  int b = blockIdx.x;
  if (b >= NJB) {  // zero the padding rows [sum(cnts), TT)
    int total = 0;
#pragma unroll
    for (int e = 0; e < NE; ++e) total += cnts[e];
    size_t base4 = (size_t)total * (DD / 4);
    size_t n4 = ((size_t)TT * DD) / 4 - base4;
    f32x4* o4 = (f32x4*)out + base4;
    f32x4 z{0.f, 0.f, 0.f, 0.f};
    for (size_t i = (size_t)(b - NJB) * 512 + threadIdx.x; i < n4;
         i += (size_t)ZBLK * 512)
      o4[i] = z;
    return;
  }

  int lin = (b & 7) * (NJB / 8) + (b >> 3);  // NJB % 8 == 0
  const int tile = lin % MT;
  const int n0 = (lin / MT) * 256;
  TileInfo ti = find_tile(cnts, tile);
  if (ti.e < 0) return;

  const bf16* w2e = w2 + (size_t)ti.e * DD * HH;
  const bf16* hb = hbuf + (size_t)ti.row0 * HH;

  __shared__ bf16 sA[3][128 * 64];  // 16 KB / buf
  __shared__ bf16 sB[3][256 * 64];  // 32 KB / buf -> 144 KB total

  const int tid = threadIdx.x;
  const int lane = tid & 63, wave = tid >> 6;
  const int wm = wave >> 2, wn = wave & 3;
  const int lr = lane & 15, lkg = (lane >> 4) & 3;

  const int r8 = tid >> 3;
  const int csw = ((tid & 7) ^ (r8 & 7)) << 3;
  const int rvm1 = ti.rv - 1;
  const int ra0 = r8 > rvm1 ? rvm1 : r8;
  const int ra1 = (64 + r8) > rvm1 ? rvm1 : 64 + r8;
  const bf16* gA0 = hb + (size_t)ra0 * HH + csw;
  const bf16* gA1 = hb + (size_t)ra1 * HH + csw;
  const bf16* gB0 = w2e + (size_t)(n0 + r8) * HH + csw;
  const bf16* gB1 = w2e + (size_t)(n0 + 64 + r8) * HH + csw;
  const bf16* gB2 = w2e + (size_t)(n0 + 128 + r8) * HH + csw;
  const bf16* gB3 = w2e + (size_t)(n0 + 192 + r8) * HH + csw;
  const int d0 = tid * 8, d1 = 4096 + tid * 8;
  const int e2 = 8192 + tid * 8, e3 = 12288 + tid * 8;

#define STAGE_B_P0(kt, bb)               \
  do {                                   \
    int kk = (kt) * 64;                  \
    gld16(gA0 + kk, &sA[bb][d0]);        \
    gld16(gA1 + kk, &sA[bb][d1]);        \
    gld16(gB0 + kk, &sB[bb][d0]);        \
    gld16(gB1 + kk, &sB[bb][d1]);        \
  } while (0)
#define STAGE_B_P1(kt, bb)               \
  do {                                   \
    int kk = (kt) * 64;                  \
    gld16(gB2 + kk, &sB[bb][e2]);        \
    gld16(gB3 + kk, &sB[bb][e3]);        \
  } while (0)

  const int s7 = lr & 7;
  const int abase = (wm * 64 + lr) * 128 + ((lkg ^ s7) << 4);  // + mt*2048
  const int bbase = (wn * 64 + lr) * 128 + ((lkg ^ s7) << 4);  // + nt*2048

  f32x4 acc[4][4];
#pragma unroll
  for (int i = 0; i < 4; ++i)
#pragma unroll
    for (int j = 0; j < 4; ++j) acc[i][j] = f32x4{0.f, 0.f, 0.f, 0.f};

  STAGE_B_P0(0, 0); STAGE_B_P1(0, 0);
  STAGE_B_P0(1, 1); STAGE_B_P1(1, 1);
  asm volatile("s_waitcnt vmcnt(6)" ::: "memory");
  BARRIER();

  int cur = 0;
  for (int kt = 0; kt < NKT; ++kt) {
    const bool pf = (kt + 2) < NKT;
    int nxt = cur + 2; if (nxt >= 3) nxt -= 3;
    const char* pA = (const char*)sA[cur];
    const char* pB = (const char*)sB[cur];

    bf16x8 af[4], bfm[4];
    // ---- phase 0 (ks=0) ----
#pragma unroll
    for (int mt = 0; mt < 4; ++mt)
      af[mt] = *(const bf16x8*)(pA + abase + mt * 2048);
#pragma unroll
    for (int nt = 0; nt < 4; ++nt)
      bfm[nt] = *(const bf16x8*)(pB + bbase + nt * 2048);
    if (pf) STAGE_B_P0(kt + 2, nxt);
    BARRIER();
    __builtin_amdgcn_s_setprio(1);
#pragma unroll
    for (int mt = 0; mt < 4; ++mt)
#pragma unroll
      for (int nt = 0; nt < 4; ++nt)
        acc[mt][nt] = mfma16(bfm[nt], af[mt], acc[mt][nt]);  // swapped operands
    __builtin_amdgcn_s_setprio(0);
    BARRIER();

    // ---- phase 1 (ks=1) ----
#pragma unroll
    for (int mt = 0; mt < 4; ++mt)
      af[mt] = *(const bf16x8*)(pA + ((abase + mt * 2048) ^ 64));
#pragma unroll
    for (int nt = 0; nt < 4; ++nt)
      bfm[nt] = *(const bf16x8*)(pB + ((bbase + nt * 2048) ^ 64));
    if (pf) STAGE_B_P1(kt + 2, nxt);
    if (pf) asm volatile("s_waitcnt vmcnt(6)" ::: "memory");
    else    asm volatile("s_waitcnt vmcnt(0)" ::: "memory");
    BARRIER();
    __builtin_amdgcn_s_setprio(1);
#pragma unroll
    for (int mt = 0; mt < 4; ++mt)
#pragma unroll
      for (int nt = 0; nt < 4; ++nt)
        acc[mt][nt] = mfma16(bfm[nt], af[mt], acc[mt][nt]);
    __builtin_amdgcn_s_setprio(0);
    BARRIER();
    cur = (cur + 1 == 3) ? 0 : cur + 1;
  }
#undef STAGE_B_P0
#undef STAGE_B_P1

  // epilogue: m = lr, n = lkg*4 + reg -> one 16 B store per fragment
#pragma unroll
  for (int mt = 0; mt < 4; ++mt) {
    int row = wm * 64 + mt * 16 + lr;
    if (row < ti.rv) {
      size_t base = (size_t)(ti.row0 + row) * DD + n0 + wn * 64 + (lkg << 2);
#pragma unroll
      for (int nt = 0; nt < 4; ++nt)
        *(f32x4*)&out[base + nt * 16] = acc[mt][nt];
    }
  }
}

extern "C" void kernel_launch(void* const* d_in, const int* in_sizes, int n_in,
                              void* d_out, int out_size, void* d_ws, size_t ws_size,
                              hipStream_t stream) {
  const float* x = (const float*)d_in[0];
  const float* w1 = (const float*)d_in[1];
  const float* w2 = (const float*)d_in[2];
  const float* w3 = (const float*)d_in[3];
  const int* cnts = (const int*)d_in[4];
  float* out = (float*)d_out;

  char* ws = (char*)d_ws;
  bf16* hbuf = (bf16*)ws;
  bf16* xb = (bf16*)(ws + XB_OFF);
  bf16* w1b = (bf16*)(ws + W1B_OFF);
  bf16* w3b = (bf16*)(ws + W3B_OFF);
  bf16* w2b = w1b;  // alias: w1b dead after GEMM A, stream-serial

  constexpr int NBX = (int)(XN / 4 / 256);
  constexpr int NBW = (int)(WN / 4 / 256);

  cvt3_k<<<NBX + 2 * NBW, 256, 0, stream>>>((const float4*)x, (const float4*)w1,
                                            (const float4*)w3, (bf16x4*)xb,
                                            (bf16x4*)w1b, (bf16x4*)w3b);

  swiglu_gemm_k<<<NJA, 512, 0, stream>>>(xb, w1b, w3b, cnts, hbuf);

  cvt_bf16_k<<<NBW, 256, 0, stream>>>((const float4*)w2, (bf16x4*)w2b, (int)(WN / 4));

  down_gemm_k<<<NJB + ZBLK, 512, 0, stream>>>(hbuf, w2b, cnts, out);
}